// Round 10
// baseline (92.208 us; speedup 1.0000x reference)
//
#include <hip/hip_runtime.h>
#include <hip/hip_bf16.h>
#include <cstddef>

#define NE 65536
#define ND 256
#define NP 8
#define RBLK 64              // routing blocks
#define EPB (NE / RBLK)      // 1024 edges per routing block
#define TR 32                // rows per main tile
#define MAXT 2056            // max tiles: 2048 + 8

typedef short bf16x8 __attribute__((ext_vector_type(8)));
typedef float f32x4  __attribute__((ext_vector_type(4)));
typedef const __attribute__((address_space(1))) unsigned int* gas_t;
typedef __attribute__((address_space(3))) unsigned int* las_t;

__device__ __forceinline__ unsigned short f2bf(float f) {
  unsigned int u = __float_as_uint(f);
  u += 0x7FFFu + ((u >> 16) & 1u);   // round-to-nearest-even
  return (unsigned short)(u >> 16);
}

// idx dtype sniff: odd 32-bit words all-zero <=> int64 (values < 8)
__device__ __forceinline__ int sniff_is32(const void* idxraw, int* lflag) {
  int tid = threadIdx.x;
  if (tid == 0) *lflag = 0;
  __syncthreads();
  const unsigned int* w = (const unsigned int*)idxraw;
  unsigned int val = w[((blockIdx.x & 63) * 256 + (tid & 255)) * 2 + 1];
  if (__any(val != 0) && (tid & 63) == 0) atomicOr(lflag, 1);
  __syncthreads();
  return *lflag;
}
__device__ __forceinline__ int load_idx(const void* idxraw, int is32, int e) {
  return is32 ? ((const int*)idxraw)[e] : (int)((const long long*)idxraw)[e];
}

// ---- phase 1: per-block LDS histogram ----
__global__ __launch_bounds__(256) void k_hist(const void* __restrict__ idxraw,
                                              int* __restrict__ counts) {
  __shared__ int h[NP];
  __shared__ int lflag;
  int tid = threadIdx.x;
  int is32 = sniff_is32(idxraw, &lflag);
  if (tid < NP) h[tid] = 0;
  __syncthreads();
  int base = blockIdx.x * EPB;
#pragma unroll
  for (int i = 0; i < EPB / 256; ++i) {
    int p = load_idx(idxraw, is32, base + tid + i * 256);
    atomicAdd(&h[p], 1);
  }
  __syncthreads();
  if (tid < NP) counts[blockIdx.x * NP + tid] = h[tid];
}

// ---- phase 2: totals, CSR offsets, 32-row tile prefix, per-block bases ----
__global__ __launch_bounds__(64) void k_scan(const int* __restrict__ counts,
                                             int* __restrict__ hdr,
                                             int* __restrict__ bases) {
  __shared__ int cnt[NP];
  __shared__ int off[NP + 1];
  int q = threadIdx.x;
  if (q < NP) {
    int s = 0;
    for (int b = 0; b < RBLK; ++b) s += counts[b * NP + q];
    cnt[q] = s;
  }
  __syncthreads();
  if (q == 0) {
    int o = 0, tt = 0;
    for (int p = 0; p < NP; ++p) {
      off[p] = o; hdr[p] = o; hdr[9 + p] = tt;
      o += cnt[p];
      tt += (cnt[p] + TR - 1) / TR;
    }
    off[NP] = o; hdr[NP] = o; hdr[9 + NP] = tt;
  }
  __syncthreads();
  if (q < NP) {
    int run = off[q];
    for (int b = 0; b < RBLK; ++b) {
      bases[b * NP + q] = run;
      run += counts[b * NP + q];
    }
  }
}

// ---- phase 3: CSR scatter with LDS cursors ----
__global__ __launch_bounds__(256) void k_scatter(const void* __restrict__ idxraw,
                                                 const int* __restrict__ bases,
                                                 int* __restrict__ perm) {
  __shared__ int cur[NP];
  __shared__ int lflag;
  int tid = threadIdx.x;
  int is32 = sniff_is32(idxraw, &lflag);
  if (tid < NP) cur[tid] = bases[blockIdx.x * NP + tid];
  __syncthreads();
  int base = blockIdx.x * EPB;
#pragma unroll
  for (int i = 0; i < EPB / 256; ++i) {
    int e = base + tid + i * 256;
    int p = load_idx(idxraw, is32, e);
    int slot = atomicAdd(&cur[p], 1);
    perm[slot] = e;
  }
}

// ---- prep: W_bil -> B-frag bf16 layout; v_p = b_lr[p] @ W_bil (fp32) ----
__global__ __launch_bounds__(256) void k_prep(const float* __restrict__ Wbil,
                                              const float* __restrict__ blr,
                                              unsigned short* __restrict__ WbT,
                                              float* __restrict__ v) {
  int b = blockIdx.x, t = threadIdx.x;
  if (b < 32) {
    int s = b * 256 + t;
    int kt = s >> 10, c = (s >> 6) & 15, l = s & 63;
    int col = c * 16 + (l & 15);
    int k0 = kt * 32 + (l >> 4) * 8;
    union { uint4 u; unsigned short h[8]; } uu;
#pragma unroll
    for (int j = 0; j < 8; ++j)
      uu.h[j] = f2bf(Wbil[(k0 + j) * ND + col]);
    *(uint4*)(WbT + (size_t)s * 8) = uu.u;
  } else {
    int p = b - 32;
    float s = 0.f;
    for (int k = 0; k < ND; ++k)
      s = fmaf(blr[p * ND + k], Wbil[k * ND + t], s);
    v[p * ND + t] = s;
  }
}

// ---- C_p = W_lr[p]^T @ W_bil  (bf16 MFMA), written in B-frag layout ----
__global__ __launch_bounds__(256) void k_cpre(const float* __restrict__ Wlr,
                                              const unsigned short* __restrict__ WbT,
                                              unsigned short* __restrict__ Cst) {
  __shared__ unsigned short aF[2048 * 8];
  int blk = blockIdx.x;
  int p = blk >> 2;
  int i0 = (blk & 3) * 64;
  int tid = threadIdx.x;
  const float* Wp = Wlr + (size_t)p * ND * ND;
#pragma unroll
  for (int it = 0; it < 8; ++it) {
    int s = tid + it * 256;
    int kt = s >> 8, r = (s >> 6) & 3, l = s & 63;
    int i = r * 16 + (l & 15);
    int k0 = kt * 32 + (l >> 4) * 8;
    union { uint4 u; unsigned short h[8]; } uu;
#pragma unroll
    for (int j = 0; j < 8; ++j)
      uu.h[j] = f2bf(Wp[(size_t)(k0 + j) * ND + i0 + i]);
    *(uint4*)(aF + (size_t)s * 8) = uu.u;
  }
  __syncthreads();
  int w = tid >> 6, l = tid & 63;
  f32x4 zero = {0.f, 0.f, 0.f, 0.f};
  f32x4 acc[16];
#pragma unroll
  for (int c = 0; c < 16; ++c) acc[c] = zero;
  for (int kt = 0; kt < 8; ++kt) {
    bf16x8 a = *(const bf16x8*)(aF + (size_t)((kt * 4 + w) * 64 + l) * 8);
#pragma unroll
    for (int c = 0; c < 16; ++c) {
      bf16x8 bb = *(const bf16x8*)(WbT + (size_t)((kt * 16 + c) * 64 + l) * 8);
      acc[c] = __builtin_amdgcn_mfma_f32_16x16x32_bf16(a, bb, acc[c], 0, 0, 0);
    }
  }
  unsigned short* Cp = Cst + (size_t)p * ND * ND;
#pragma unroll
  for (int c = 0; c < 16; ++c) {
#pragma unroll
    for (int q = 0; q < 4; ++q) {
      int i = i0 + w * 16 + ((l >> 4) * 4) + q;
      int j = c * 16 + (l & 15);
      int pos = ((i >> 5) * 16 + (j >> 4)) * 512 + (((i >> 3) & 3) * 16 + (j & 15)) * 8 + (i & 7);
      Cp[pos] = f2bf(acc[c][q]);
    }
  }
}

// ---- main v10: 32-row CSR tiles; z_src/z_dst staged RAW fp32 via
// global_load_lds width=16 (async, no VGPR round-trip; 8 instrs/wave all in
// flight). LDS dest is linear; the per-lane GLOBAL address is pre-swizzled
// (pair-level XOR by row&3) so A-frag ds_reads and epilogue reads are
// bank-spread. fp32->bf16 conversion happens per-A-frag in the GEMM loop;
// epilogue consumes fp32 z_dst directly.
__global__ __launch_bounds__(512, 4) void k_main(const float* __restrict__ zsrc,
                                                 const float* __restrict__ zdst,
                                                 const int* __restrict__ perm,
                                                 const int* __restrict__ hdr,
                                                 const unsigned short* __restrict__ Cst,
                                                 const float* __restrict__ v,
                                                 const float* __restrict__ bbil,
                                                 float* __restrict__ out) {
  __shared__ float zsF[TR * 256];        // 32 KiB zsrc tile fp32, pair-swizzled
  __shared__ float zdF[TR * 256];        // 32 KiB zdst tile fp32, pair-swizzled
  __shared__ float red[8][TR];           // 1 KiB
  __shared__ int eids[TR];
  __shared__ int shdr[18];
  int tid = threadIdx.x;
  if (tid < 18) shdr[tid] = hdr[tid];
  __syncthreads();
  int bid = blockIdx.x;
  if (bid >= shdr[9 + NP]) return;
  int p = 0;
  while (p < NP - 1 && bid >= shdr[9 + p + 1]) ++p;
  int t = bid - shdr[9 + p];
  int cnt = shdr[p + 1] - shdr[p];
  int ebase = shdr[p] + t * TR;
  int nrow = cnt - t * TR; if (nrow > TR) nrow = TR;
  if (tid < TR) eids[tid] = perm[ebase + (tid < nrow ? tid : nrow - 1)];
  __syncthreads();
  int w = tid >> 6, l = tid & 63;

  // ---- async staging: wave w owns rows w*4..w*4+3 of both arrays ----
#pragma unroll
  for (int i = 0; i < 4; ++i) {
    int row = w * 4 + i;
    int e = eids[row];
    int s = row & 3;
    // lane l fills LDS granule l of this row; source granule pair-XOR'd
    unsigned srcoff = ((((unsigned)(l >> 1) ^ (unsigned)s) << 5) | ((unsigned)(l & 1) << 4));
    const float* gs = zsrc + (size_t)e * ND + (srcoff >> 2);
    const float* gd = zdst + (size_t)e * ND + (srcoff >> 2);
    __builtin_amdgcn_global_load_lds((gas_t)(const void*)gs,
                                     (las_t)(void*)((char*)zsF + row * 1024), 16, 0, 0);
    __builtin_amdgcn_global_load_lds((gas_t)(const void*)gd,
                                     (las_t)(void*)((char*)zdF + row * 1024), 16, 0, 0);
  }
  __syncthreads();   // drains vmcnt: tiles resident

  // ---- GEMM: wave w covers col-tiles {2w, 2w+1}; 2 row-strips ----
  const unsigned short* Cp = Cst + (size_t)p * ND * ND;
  f32x4 zero = {0.f, 0.f, 0.f, 0.f};
  f32x4 acc[2][2];
#pragma unroll
  for (int sr = 0; sr < 2; ++sr)
#pragma unroll
    for (int cl = 0; cl < 2; ++cl) acc[sr][cl] = zero;
  int hh = l >> 4, rr = l & 15;
#pragma unroll
  for (int kt = 0; kt < 8; ++kt) {
    bf16x8 a[2];
#pragma unroll
    for (int sr = 0; sr < 2; ++sr) {
      int row = sr * 16 + rr;
      unsigned pidx = (unsigned)((kt * 4 + hh) ^ (row & 3));
      const char* bp = (const char*)zsF + row * 1024 + (pidx << 5);
      float4 f0 = *(const float4*)(bp);
      float4 f1 = *(const float4*)(bp + 16);
      union { bf16x8 vv; unsigned short h[8]; } ua;
      ua.h[0] = f2bf(f0.x); ua.h[1] = f2bf(f0.y); ua.h[2] = f2bf(f0.z); ua.h[3] = f2bf(f0.w);
      ua.h[4] = f2bf(f1.x); ua.h[5] = f2bf(f1.y); ua.h[6] = f2bf(f1.z); ua.h[7] = f2bf(f1.w);
      a[sr] = ua.vv;
    }
#pragma unroll
    for (int cl = 0; cl < 2; ++cl) {
      bf16x8 bb = *(const bf16x8*)(Cp + (size_t)((kt * 16 + (w * 2 + cl)) * 64 + l) * 8);
#pragma unroll
      for (int sr = 0; sr < 2; ++sr)
        acc[sr][cl] = __builtin_amdgcn_mfma_f32_16x16x32_bf16(a[sr], bb, acc[sr][cl], 0, 0, 0);
    }
  }

  // ---- fused epilogue: fp32 z_dst from LDS; 4-lane-group reduce ----
  float vloc[2];
#pragma unroll
  for (int cl = 0; cl < 2; ++cl)
    vloc[cl] = v[p * ND + (w * 2 + cl) * 16 + rr];
#pragma unroll
  for (int sr = 0; sr < 2; ++sr) {
#pragma unroll
    for (int q = 0; q < 4; ++q) {
      int row = sr * 16 + hh * 4 + q;          // D-layout: col=l&15, row=(l>>4)*4+reg
      int s = row & 3;
      float sv = 0.f;
#pragma unroll
      for (int cl = 0; cl < 2; ++cl) {
        int col = (w * 2 + cl) * 16 + rr;
        unsigned byte = (unsigned)(row * 1024) + ((((unsigned)(col >> 3) ^ (unsigned)s) << 5) | ((unsigned)(col & 7) << 2));
        float zv = *(const float*)((const char*)zdF + byte);
        sv = fmaf(acc[sr][cl][q] + vloc[cl], zv, sv);
      }
      sv += __shfl_xor(sv, 1, 64);
      sv += __shfl_xor(sv, 2, 64);
      sv += __shfl_xor(sv, 4, 64);
      sv += __shfl_xor(sv, 8, 64);
      if (rr == 0) red[w][row] = sv;
    }
  }
  __syncthreads();
  if (tid < TR && tid < nrow) {
    float sc = bbil[0];
#pragma unroll
    for (int ww = 0; ww < 8; ++ww) sc += red[ww][tid];
    out[eids[tid]] = sc;
  }
}

extern "C" void kernel_launch(void* const* d_in, const int* in_sizes, int n_in,
                              void* d_out, int out_size, void* d_ws, size_t ws_size,
                              hipStream_t stream) {
  // setup_inputs() dict order: z_src, z_dst, W_lr, b_lr, W_bil, b_bil, lr_pair_idx
  const float* zsrc = (const float*)d_in[0];
  const float* zdst = (const float*)d_in[1];
  const float* Wlr  = (const float*)d_in[2];
  const float* blr  = (const float*)d_in[3];
  const float* Wbil = (const float*)d_in[4];
  const float* bbil = (const float*)d_in[5];
  const void*  idx  = (const void*)d_in[6];
  float* out = (float*)d_out;

  char* ws = (char*)d_ws;
  int* hdr    = (int*)ws;                                  // 72 B
  int* counts = (int*)(ws + 4096);                         // 2 KiB
  int* bases  = (int*)(ws + 8192);                         // 2 KiB
  int* perm   = (int*)(ws + 16384);                        // 256 KiB (CSR)
  unsigned short* WbT = (unsigned short*)(ws + 16384 + (size_t)NE * 4);            // 128 KiB
  float* v = (float*)(ws + 16384 + (size_t)NE * 4 + 131072);                       // 8 KiB
  unsigned short* Cst = (unsigned short*)(ws + 16384 + (size_t)NE * 4 + 131072 + 8192); // 1 MiB

  k_prep<<<40, 256, 0, stream>>>(Wbil, blr, WbT, v);
  k_hist<<<RBLK, 256, 0, stream>>>(idx, counts);
  k_scan<<<1, 64, 0, stream>>>(counts, hdr, bases);
  k_scatter<<<RBLK, 256, 0, stream>>>(idx, bases, perm);
  k_cpre<<<32, 256, 0, stream>>>(Wlr, WbT, Cst);
  k_main<<<MAXT, 512, 0, stream>>>(zsrc, zdst, perm, hdr, Cst, v, bbil, out);
}